// Round 6
// baseline (122.076 us; speedup 1.0000x reference)
//
#include <hip/hip_runtime.h>
#include <cstdint>
#include <cstddef>

// predictions: (16, 3, 160, 160, 9) fp32 -> per image N=76800 anchors x D=9
// targets:     (16, 32, 5) fp32 [cls, x, y, w, h]
// output: 4 fp32 scalars: total, box_loss, cls_loss, obj_loss
constexpr int kB     = 16;
constexpr int kN     = 76800;
constexpr int kD     = 9;
constexpr int kT     = 32;
constexpr int kBlk1  = 256;          // K1 block (1 anchor/thread)
constexpr int kNB1   = kN / kBlk1;   // 300 K1 blocks per image
constexpr int kBlk3  = 512;          // K2 block
constexpr int kNB3   = kN / kBlk3;   // 150 K2 blocks per image
constexpr int kWords = kN / 64;      // 1200 ballot words per image

// jax.nn.softplus(x) == max(x,0) + log1p(exp(-|x|))
__device__ __forceinline__ float softplusf(float x) {
  return fmaxf(x, 0.f) + log1pf(expf(-fabsf(x)));
}

// broadcast lane j's float to all lanes via v_readlane (VALU only, no LDS/SMEM)
__device__ __forceinline__ float rlane(float x, int j) {
  return __int_as_float(__builtin_amdgcn_readlane(__float_as_int(x), j));
}

// ---------------------------------------------------------------------------
// K1: 1 anchor/thread. Targets derived per-lane (lane&31) once, broadcast via
// v_readlane in the unrolled loop. Division-free threshold tests:
//   iou>0.5 <=> d>=0 && inter>0.5*d    (d = ((pa+ta)-inter)+1e-6)
//   iou<0.3 <=> d<0  || inter<0.3*d
// Outputs: per-block cnt/nneg/objP/objN (distinct slots, no atomics) + posBits.
// ---------------------------------------------------------------------------
__global__ __launch_bounds__(kBlk1) void k1_iou_kernel(
    const float* __restrict__ pred, const float* __restrict__ tgt,
    int* __restrict__ cnt, int* __restrict__ nnegA,
    float* __restrict__ objP, float* __restrict__ objN,
    unsigned long long* __restrict__ posBits)
{
  __shared__ float s_red[4][2];
  __shared__ int   s_cnt[4][2];

  const int b   = blockIdx.y;
  const int blk = blockIdx.x;
  const int tid = threadIdx.x;
  const int lane = tid & 63;
  const int wv   = tid >> 6;

  // per-lane target (lane&31): derive box corners + area (reference order)
  const float* tp = tgt + ((size_t)b * kT + (lane & 31)) * 5;
  const float ttx = tp[1], tty = tp[2], ttw = tp[3], tth = tp[4];
  const float v1x = ttx - ttw * 0.5f, v1y = tty - tth * 0.5f;
  const float v2x = ttx + ttw * 0.5f, v2y = tty + tth * 0.5f;
  const float vta = (v2x - v1x) * (v2y - v1y);   // prod(t2-t1)

  const int i = blk * kBlk1 + tid;
  const float* p = pred + ((size_t)b * kN + i) * kD;
  const float px = p[0], py = p[1], pw = p[2], ph = p[3], pobj = p[4];
  const float p1x = px - pw * 0.5f, p1y = py - ph * 0.5f;
  const float p2x = px + pw * 0.5f, p2y = py + ph * 0.5f;
  const float pa  = (p2x - p1x) * (p2y - p1y);

  bool posAny = false, negAll = true;
  #pragma unroll
  for (int j = 0; j < kT; ++j) {
    const float t1x = rlane(v1x, j);
    const float t1y = rlane(v1y, j);
    const float t2x = rlane(v2x, j);
    const float t2y = rlane(v2y, j);
    const float ta  = rlane(vta, j);
    const float lox = fmaxf(p1x, t1x), loy = fmaxf(p1y, t1y);
    const float hix = fminf(p2x, t2x), hiy = fminf(p2y, t2y);
    const float inter = fmaxf(hix - lox, 0.f) * fmaxf(hiy - loy, 0.f);
    const float d = ((pa + ta) - inter) + 1e-6f;   // reference eval order
    posAny = posAny || ((d >= 0.f) && (inter > 0.5f * d));
    negAll = negAll && ((d <  0.f) || (inter < 0.3f * d));
  }
  const bool pos = posAny;
  const bool neg = negAll;

  const float op = pos ? softplusf(-pobj) : 0.f;
  const float on = neg ? softplusf( pobj) : 0.f;

  const unsigned long long pmask = __ballot(pos);
  const unsigned long long nmask = __ballot(neg);
  if (lane == 0)
    posBits[(size_t)b * kWords + blk * 4 + wv] = pmask;

  float rop = op, ron = on;
  #pragma unroll
  for (int off = 32; off > 0; off >>= 1) {
    rop += __shfl_down(rop, off, 64);
    ron += __shfl_down(ron, off, 64);
  }
  if (lane == 0) {
    s_red[wv][0] = rop;              s_red[wv][1] = ron;
    s_cnt[wv][0] = __popcll(pmask);  s_cnt[wv][1] = __popcll(nmask);
  }
  __syncthreads();
  if (tid == 0) {
    float sop = 0.f, son = 0.f; int pc = 0, nc = 0;
    #pragma unroll
    for (int w = 0; w < 4; ++w) {
      sop += s_red[w][0]; son += s_red[w][1];
      pc  += s_cnt[w][0]; nc  += s_cnt[w][1];
    }
    const int slot = b * kNB1 + blk;   // one writer per slot, no atomics
    cnt[slot]   = pc;
    nnegA[slot] = nc;
    objP[slot]  = sop;
    objN[slot]  = son;
  }
}

// ---------------------------------------------------------------------------
// K2: positives only (512 thr, 150 blocks/image). Ordinal base = in-block sum
// of cnt[0..2blk-1] (replaces the separate scan kernel) + in-wave ballot
// prefix. Accumulates box SSE + class CE into per-block partials.
// ---------------------------------------------------------------------------
__global__ __launch_bounds__(kBlk3) void k2_pos_kernel(
    const float* __restrict__ pred, const float* __restrict__ tgt,
    const int* __restrict__ cnt,
    const unsigned long long* __restrict__ posBits,
    float* __restrict__ p3sq, float* __restrict__ p3ce)
{
  __shared__ float s_tx[kT], s_ty[kT];
  __shared__ int   s_tc[kT];
  __shared__ int   s_wtot[8];
  __shared__ int   s_cred[8];
  __shared__ float s_red[8][2];

  const int b = blockIdx.y, blk = blockIdx.x, tid = threadIdx.x;
  const int slot = b * kNB3 + blk;
  const int lane = tid & 63, wv = tid >> 6;          // wv in 0..7
  const unsigned long long mask = posBits[(size_t)b * kWords + blk * 8 + wv];
  if (lane == 0) s_wtot[wv] = __popcll(mask);

  // positives in earlier K1-blocks of this image: sum cnt[0 .. 2*blk-1]
  int c = (tid < 2 * blk) ? cnt[b * kNB1 + tid] : 0;   // 2*blk <= 298 < 512
  #pragma unroll
  for (int off = 32; off > 0; off >>= 1) c += __shfl_down(c, off, 64);
  if (lane == 0) s_cred[wv] = c;

  if (tid < kT) {
    const float* tp = tgt + ((size_t)b * kT + tid) * 5;
    s_tx[tid] = tp[1]; s_ty[tid] = tp[2];
    s_tc[tid] = (int)tp[0];
  }
  __syncthreads();

  int tot = 0, base = 0;
  #pragma unroll
  for (int w = 0; w < 8; ++w) { tot += s_wtot[w]; base += s_cred[w]; }
  if (tot == 0) {                                    // still define the slot
    if (tid == 0) { p3sq[slot] = 0.f; p3ce[slot] = 0.f; }
    return;
  }
  for (int w = 0; w < wv; ++w) base += s_wtot[w];

  const bool pos = (mask >> lane) & 1ull;
  float sqc = 0.f, cec = 0.f;
  if (pos) {
    const int ord = base + __popcll(mask & ((1ull << lane) - 1ull));
    const int tix = ord & (kT - 1);                  // % 32, ord >= 0
    const int i = blk * kBlk3 + tid;
    const float* p = pred + ((size_t)b * kN + i) * kD;
    const float dx = p[0] - s_tx[tix];
    const float dy = p[1] - s_ty[tix];
    sqc = dx * dx + dy * dy;
    const float c0 = p[5], c1 = p[6], c2 = p[7], c3 = p[8];
    const float m = fmaxf(fmaxf(c0, c1), fmaxf(c2, c3));
    const float lse = m + logf(expf(c0 - m) + expf(c1 - m) + expf(c2 - m) + expf(c3 - m));
    const int tc = s_tc[tix];
    const float cv = (tc == 0) ? c0 : (tc == 1) ? c1 : (tc == 2) ? c2 : c3;
    cec = lse - cv;
  }
  #pragma unroll
  for (int off = 32; off > 0; off >>= 1) {
    sqc += __shfl_down(sqc, off, 64);
    cec += __shfl_down(cec, off, 64);
  }
  if (lane == 0) { s_red[wv][0] = sqc; s_red[wv][1] = cec; }
  __syncthreads();
  if (tid == 0) {
    float ss = 0.f, cs = 0.f;
    #pragma unroll
    for (int w = 0; w < 8; ++w) { ss += s_red[w][0]; cs += s_red[w][1]; }
    p3sq[slot] = ss;                                 // plain store
    p3ce[slot] = cs;
  }
}

// ---------------------------------------------------------------------------
// K3: reduce all per-block partials, finalize 4 scalars.  1 block x 512:
// 32-lane group per image.
// ---------------------------------------------------------------------------
__global__ __launch_bounds__(512) void k3_final_kernel(
    const int* __restrict__ cnt, const int* __restrict__ nnegA,
    const float* __restrict__ objP, const float* __restrict__ objN,
    const float* __restrict__ p3sq, const float* __restrict__ p3ce,
    float* __restrict__ out)
{
  __shared__ float s_box[kB], s_cls[kB], s_obj[kB];
  const int tid = threadIdx.x;
  const int b = tid >> 5;                            // image 0..15
  const int l = tid & 31;

  int   np = 0, nn = 0;
  float op = 0.f, on = 0.f, sq = 0.f, ce = 0.f;
  for (int k = l; k < kNB1; k += 32) {
    np += cnt[b * kNB1 + k];
    nn += nnegA[b * kNB1 + k];
    op += objP[b * kNB1 + k];
    on += objN[b * kNB1 + k];
  }
  for (int k = l; k < kNB3; k += 32) {
    sq += p3sq[b * kNB3 + k];
    ce += p3ce[b * kNB3 + k];
  }
  #pragma unroll
  for (int off = 16; off > 0; off >>= 1) {
    np += __shfl_down(np, off, 32);
    nn += __shfl_down(nn, off, 32);
    op += __shfl_down(op, off, 32);
    on += __shfl_down(on, off, 32);
    sq += __shfl_down(sq, off, 32);
    ce += __shfl_down(ce, off, 32);
  }
  if (l == 0) {
    float box = 0.f, cls = 0.f, obj = 0.f;
    const float np_ = (float)np;
    const float nn_ = (float)nn;
    if (np_ > 0.f) {
      box = sq / (2.0f * np_);
      cls = ce / np_;
      obj = op / np_;
    }
    if (nn_ > 0.f) obj += on / nn_;
    s_box[b] = box; s_cls[b] = cls; s_obj[b] = obj;
  }
  __syncthreads();
  if (tid == 0) {
    float box = 0.f, cls = 0.f, obj = 0.f;
    #pragma unroll
    for (int bb = 0; bb < kB; ++bb) { box += s_box[bb]; cls += s_cls[bb]; obj += s_obj[bb]; }
    box *= (1.f / 16.f); cls *= (1.f / 16.f); obj *= (1.f / 16.f);
    out[0] = 0.05f * box + 0.5f * cls + 1.0f * obj;
    out[1] = box;
    out[2] = cls;
    out[3] = obj;
  }
}

// ---------------------------------------------------------------------------
extern "C" void kernel_launch(void* const* d_in, const int* in_sizes, int n_in,
                              void* d_out, int out_size, void* d_ws, size_t ws_size,
                              hipStream_t stream)
{
  const float* pred = (const float*)d_in[0];
  const float* tgt  = (const float*)d_in[1];
  float* out = (float*)d_out;

  char* ws = (char*)d_ws;
  int*   cnt    = (int*)(ws);                        // 19200 B
  int*   nnegA  = (int*)(ws + 19200);                // 19200 B
  float* objP   = (float*)(ws + 38400);              // 19200 B
  float* objN   = (float*)(ws + 57600);              // 19200 B
  unsigned long long* posBits =
      (unsigned long long*)(ws + 76800);             // 153600 B (8-aligned)
  float* p3sq   = (float*)(ws + 230400);             // 9600 B
  float* p3ce   = (float*)(ws + 240000);             // 9600 B -> 249600 total

  // every ws word read is written earlier this call: no memset needed.
  k1_iou_kernel<<<dim3(kNB1, kB), kBlk1, 0, stream>>>(
      pred, tgt, cnt, nnegA, objP, objN, posBits);
  k2_pos_kernel<<<dim3(kNB3, kB), kBlk3, 0, stream>>>(
      pred, tgt, cnt, posBits, p3sq, p3ce);
  k3_final_kernel<<<1, 512, 0, stream>>>(
      cnt, nnegA, objP, objN, p3sq, p3ce, out);
}

// Round 7
// 119.858 us; speedup vs baseline: 1.0185x; 1.0185x over previous
//
#include <hip/hip_runtime.h>
#include <cstdint>
#include <cstddef>

// predictions: (16, 3, 160, 160, 9) fp32 -> per image N=76800 anchors x D=9
// targets:     (16, 32, 5) fp32 [cls, x, y, w, h]
// output: 4 fp32 scalars: total, box_loss, cls_loss, obj_loss
constexpr int kB     = 16;
constexpr int kN     = 76800;
constexpr int kD     = 9;
constexpr int kT     = 32;
constexpr int kBlk1  = 256;            // K1 threads; 4 anchors/thread
constexpr int kApB   = 1024;           // anchors per K1/K2 block
constexpr int kNB    = kN / kApB;      // 75 blocks per image
constexpr int kWords = kN / 64;        // 1200 ballot words per image (4 per 256-chunk)

struct ImgStats { int npos; int nneg; float objPos; float objNeg; };

// jax.nn.softplus(x) == max(x,0) + log1p(exp(-|x|))
__device__ __forceinline__ float softplusf(float x) {
  return fmaxf(x, 0.f) + log1pf(expf(-fabsf(x)));
}

// ---------------------------------------------------------------------------
// Pass 0: derived target boxes, SoA: twork[b][comp][j], comp={t1x,t1y,t2x,t2y,ta}
// ---------------------------------------------------------------------------
__global__ __launch_bounds__(kB * kT) void pass0_kernel(
    const float* __restrict__ tgt, float* __restrict__ twork)
{
  const int t = threadIdx.x;           // 0..511
  const int b = t >> 5, j = t & 31;
  const float* tp = tgt + ((size_t)b * kT + j) * 5;
  const float tx = tp[1], ty = tp[2], tw = tp[3], th = tp[4];
  const float t1x = tx - tw * 0.5f, t1y = ty - th * 0.5f;
  const float t2x = tx + tw * 0.5f, t2y = ty + th * 0.5f;
  float* w = twork + (size_t)b * 5 * kT;
  w[0 * kT + j] = t1x;
  w[1 * kT + j] = t1y;
  w[2 * kT + j] = t2x;
  w[3 * kT + j] = t2y;
  w[4 * kT + j] = (t2x - t1x) * (t2y - t1y);   // reference: prod(t2-t1)
}

// ---------------------------------------------------------------------------
// K1: 4 anchors/thread via 8 aligned float4 loads (fields 0-4 of each anchor;
// cls quad skipped). Division-free threshold tests. Ballot per k-slot:
// anchor = chunk*256 + 4*lane + k; word (chunk*4+k), bit = lane.
// Per-block partials to distinct slots; no atomics.
// ---------------------------------------------------------------------------
__global__ __launch_bounds__(kBlk1) void k1_iou_kernel(
    const float* __restrict__ pred, const float* __restrict__ twork,
    int* __restrict__ cnt, int* __restrict__ nnegA,
    float* __restrict__ objP, float* __restrict__ objN,
    unsigned long long* __restrict__ posBits)
{
  __shared__ float s_red[4][2];
  __shared__ int   s_cnt[4][2];

  const int b    = blockIdx.y;
  const int blk  = blockIdx.x;
  const int tid  = threadIdx.x;
  const int lane = tid & 63;
  const int wv   = tid >> 6;
  const float* tw = twork + (size_t)b * 5 * kT;     // wave-uniform base

  // thread's 4 anchors: a0 = blk*1024 + wv*256 + 4*lane
  const int a0 = blk * kApB + wv * 256 + 4 * lane;
  const float4* q = reinterpret_cast<const float4*>(
      pred + ((size_t)b * kN + a0) * kD);
  const float4 q0 = q[0], q1 = q[1], q2 = q[2], q3 = q[3];
  const float4 q4 = q[4], q5 = q[5], q6 = q[6], q7 = q[7];

  // field map: anchor k flat indices 9k..9k+4
  float px[4], py[4], pw_[4], ph[4], pobj[4];
  px[0]=q0.x; py[0]=q0.y; pw_[0]=q0.z; ph[0]=q0.w; pobj[0]=q1.x;
  px[1]=q2.y; py[1]=q2.z; pw_[1]=q2.w; ph[1]=q3.x; pobj[1]=q3.y;
  px[2]=q4.z; py[2]=q4.w; pw_[2]=q5.x; ph[2]=q5.y; pobj[2]=q5.z;
  px[3]=q6.w; py[3]=q7.x; pw_[3]=q7.y; ph[3]=q7.z; pobj[3]=q7.w;

  float p1x[4], p1y[4], p2x[4], p2y[4], pa[4];
  #pragma unroll
  for (int k = 0; k < 4; ++k) {
    p1x[k] = px[k] - pw_[k] * 0.5f;  p1y[k] = py[k] - ph[k] * 0.5f;
    p2x[k] = px[k] + pw_[k] * 0.5f;  p2y[k] = py[k] + ph[k] * 0.5f;
    pa[k]  = (p2x[k] - p1x[k]) * (p2y[k] - p1y[k]);
  }

  bool posA[4] = {false,false,false,false};
  bool negA[4] = {true,true,true,true};
  #pragma unroll
  for (int j = 0; j < kT; ++j) {
    const float t1x = tw[0 * kT + j];
    const float t1y = tw[1 * kT + j];
    const float t2x = tw[2 * kT + j];
    const float t2y = tw[3 * kT + j];
    const float ta  = tw[4 * kT + j];
    #pragma unroll
    for (int k = 0; k < 4; ++k) {
      const float lox = fmaxf(p1x[k], t1x), loy = fmaxf(p1y[k], t1y);
      const float hix = fminf(p2x[k], t2x), hiy = fminf(p2y[k], t2y);
      const float inter = fmaxf(hix - lox, 0.f) * fmaxf(hiy - loy, 0.f);
      const float d = ((pa[k] + ta) - inter) + 1e-6f;   // reference eval order
      posA[k] = posA[k] || ((d >= 0.f) && (inter > 0.5f * d));
      negA[k] = negA[k] && ((d <  0.f) || (inter < 0.3f * d));
    }
  }

  float op = 0.f, on = 0.f;
  int pc = 0, nc = 0;
  const int chunk = blk * 4 + wv;                    // global 256-anchor chunk
  #pragma unroll
  for (int k = 0; k < 4; ++k) {
    op += posA[k] ? softplusf(-pobj[k]) : 0.f;
    on += negA[k] ? softplusf( pobj[k]) : 0.f;
    const unsigned long long pm = __ballot(posA[k]);
    const unsigned long long nm = __ballot(negA[k]);
    if (lane == 0)
      posBits[(size_t)b * kWords + chunk * 4 + k] = pm;
    pc += __popcll(pm);
    nc += __popcll(nm);
  }

  #pragma unroll
  for (int off = 32; off > 0; off >>= 1) {
    op += __shfl_down(op, off, 64);
    on += __shfl_down(on, off, 64);
  }
  if (lane == 0) {
    s_red[wv][0] = op;  s_red[wv][1] = on;
    s_cnt[wv][0] = pc;  s_cnt[wv][1] = nc;
  }
  __syncthreads();
  if (tid == 0) {
    float sop = 0.f, son = 0.f; int tpc = 0, tnc = 0;
    #pragma unroll
    for (int w = 0; w < 4; ++w) {
      sop += s_red[w][0]; son += s_red[w][1];
      tpc += s_cnt[w][0]; tnc += s_cnt[w][1];
    }
    const int slot = b * kNB + blk;                  // one writer, no atomics
    cnt[slot]   = tpc;
    nnegA[slot] = tnc;
    objP[slot]  = sop;
    objN[slot]  = son;
  }
}

// ---------------------------------------------------------------------------
// Pass 2: per image — exclusive scan of 75 block counts + reduce stats.
// ---------------------------------------------------------------------------
__global__ __launch_bounds__(512) void pass2_kernel(
    const int* __restrict__ cnt, const int* __restrict__ nnegA,
    const float* __restrict__ objP, const float* __restrict__ objN,
    int* __restrict__ blockOffsets, ImgStats* __restrict__ stats)
{
  __shared__ int s[512];
  __shared__ float s_op[8], s_on[8];
  __shared__ int   s_nn[8];

  const int b = blockIdx.x, t = threadIdx.x;
  const bool live = (t < kNB);
  const int v = live ? cnt[b * kNB + t] : 0;
  int   nn = live ? nnegA[b * kNB + t] : 0;
  float op = live ? objP[b * kNB + t] : 0.f;
  float on = live ? objN[b * kNB + t] : 0.f;

  s[t] = v;
  __syncthreads();
  for (int off = 1; off < 512; off <<= 1) {
    const int add = (t >= off) ? s[t - off] : 0;
    __syncthreads();
    s[t] += add;
    __syncthreads();
  }
  if (live) blockOffsets[b * kNB + t] = s[t] - v;   // exclusive

  const int lane = t & 63, wv = t >> 6;
  #pragma unroll
  for (int off = 32; off > 0; off >>= 1) {
    nn += __shfl_down(nn, off, 64);
    op += __shfl_down(op, off, 64);
    on += __shfl_down(on, off, 64);
  }
  if (lane == 0) { s_nn[wv] = nn; s_op[wv] = op; s_on[wv] = on; }
  __syncthreads();
  if (t == 0) {
    int tn = 0; float top = 0.f, ton = 0.f;
    #pragma unroll
    for (int w = 0; w < 8; ++w) { tn += s_nn[w]; top += s_op[w]; ton += s_on[w]; }
    ImgStats st;
    st.npos = s[511];             // inclusive total (zeros padded above kNB)
    st.nneg = tn;
    st.objPos = top;
    st.objNeg = ton;
    stats[b] = st;
  }
}

// ---------------------------------------------------------------------------
// K2: positives only. 256 thr/block, 4 chunks/block (wave wv owns chunk wv),
// 4 anchors/thread, interleaved rank math matching K1's ballot layout.
// ---------------------------------------------------------------------------
__global__ __launch_bounds__(kBlk1) void k2_pos_kernel(
    const float* __restrict__ pred, const float* __restrict__ tgt,
    const int* __restrict__ blockOffsets,
    const unsigned long long* __restrict__ posBits,
    float* __restrict__ p3sq, float* __restrict__ p3ce)
{
  __shared__ float s_tx[kT], s_ty[kT];
  __shared__ int   s_tc[kT];
  __shared__ int   s_ctot[4];
  __shared__ float s_red[4][2];

  const int b = blockIdx.y, blk = blockIdx.x, tid = threadIdx.x;
  const int slot = b * kNB + blk;
  const int lane = tid & 63, wv = tid >> 6;

  // wave wv's chunk: 4 ballot words (wave-uniform address -> scalar loads)
  const unsigned long long* wp =
      posBits + (size_t)b * kWords + (blk * 4 + wv) * 4;
  const unsigned long long m0 = wp[0], m1 = wp[1], m2 = wp[2], m3 = wp[3];
  const int ctot = __popcll(m0) + __popcll(m1) + __popcll(m2) + __popcll(m3);
  if (lane == 0) s_ctot[wv] = ctot;

  if (tid < kT) {
    const float* tp = tgt + ((size_t)b * kT + tid) * 5;
    s_tx[tid] = tp[1]; s_ty[tid] = tp[2];
    s_tc[tid] = (int)tp[0];
  }
  __syncthreads();

  int tot = 0;
  #pragma unroll
  for (int c = 0; c < 4; ++c) tot += s_ctot[c];
  if (tot == 0) {                                    // still define the slot
    if (tid == 0) { p3sq[slot] = 0.f; p3ce[slot] = 0.f; }
    return;
  }

  int base = blockOffsets[b * kNB + blk];
  for (int c = 0; c < wv; ++c) base += s_ctot[c];

  // rank prelude for this lane within its chunk
  const unsigned long long low = ((unsigned long long)1 << lane) - 1ull;
  const int beforeLanes = __popcll(m0 & low) + __popcll(m1 & low)
                        + __popcll(m2 & low) + __popcll(m3 & low);
  const int bit0 = (int)((m0 >> lane) & 1ull);
  const int bit1 = (int)((m1 >> lane) & 1ull);
  const int bit2 = (int)((m2 >> lane) & 1ull);
  const int bit3 = (int)((m3 >> lane) & 1ull);
  const int kbit[4] = {bit0, bit1, bit2, bit3};

  const int a0 = blk * kApB + wv * 256 + 4 * lane;   // thread's first anchor
  float sqc = 0.f, cec = 0.f;
  int prior = 0;                                     // same-lane earlier-k positives
  #pragma unroll
  for (int k = 0; k < 4; ++k) {
    if (kbit[k]) {
      const int ord = base + beforeLanes + prior;
      const int tix = ord & (kT - 1);                // % 32
      const float* p = pred + ((size_t)b * kN + (a0 + k)) * kD;
      const float dx = p[0] - s_tx[tix];
      const float dy = p[1] - s_ty[tix];
      sqc += dx * dx + dy * dy;
      const float c0 = p[5], c1 = p[6], c2 = p[7], c3 = p[8];
      const float m = fmaxf(fmaxf(c0, c1), fmaxf(c2, c3));
      const float lse = m + logf(expf(c0 - m) + expf(c1 - m) + expf(c2 - m) + expf(c3 - m));
      const int tc = s_tc[tix];
      const float cv = (tc == 0) ? c0 : (tc == 1) ? c1 : (tc == 2) ? c2 : c3;
      cec += lse - cv;
    }
    prior += kbit[k];
  }

  #pragma unroll
  for (int off = 32; off > 0; off >>= 1) {
    sqc += __shfl_down(sqc, off, 64);
    cec += __shfl_down(cec, off, 64);
  }
  if (lane == 0) { s_red[wv][0] = sqc; s_red[wv][1] = cec; }
  __syncthreads();
  if (tid == 0) {
    float ss = 0.f, cs = 0.f;
    #pragma unroll
    for (int w = 0; w < 4; ++w) { ss += s_red[w][0]; cs += s_red[w][1]; }
    p3sq[slot] = ss;                                 // plain store
    p3ce[slot] = cs;
  }
}

// ---------------------------------------------------------------------------
// Pass 4: reduce per-block partials (75/image), finalize 4 scalars.
// ---------------------------------------------------------------------------
__global__ __launch_bounds__(256) void pass4_kernel(
    const ImgStats* __restrict__ stats,
    const float* __restrict__ p3sq, const float* __restrict__ p3ce,
    float* __restrict__ out)
{
  __shared__ float s_sq[16][17], s_ce[16][17];
  const int tid = threadIdx.x;
  const int b = tid & 15, g = tid >> 4;              // image, group
  float sq = 0.f, ce = 0.f;
  for (int k = g; k < kNB; k += 16) {
    sq += p3sq[b * kNB + k];
    ce += p3ce[b * kNB + k];
  }
  s_sq[g][b] = sq; s_ce[g][b] = ce;
  __syncthreads();

  float box = 0.f, cls = 0.f, obj = 0.f;
  if (tid < kB) {
    float ssq = 0.f, sce = 0.f;
    #pragma unroll
    for (int gg = 0; gg < 16; ++gg) { ssq += s_sq[gg][tid]; sce += s_ce[gg][tid]; }
    const ImgStats st = stats[tid];
    const float np_ = (float)st.npos;
    const float nn  = (float)st.nneg;
    if (np_ > 0.f) {
      box = ssq / (2.0f * np_);
      cls = sce / np_;
      obj = st.objPos / np_;
    }
    if (nn > 0.f) obj += st.objNeg / nn;
  }
  #pragma unroll
  for (int off = 8; off > 0; off >>= 1) {
    box += __shfl_down(box, off, 64);
    cls += __shfl_down(cls, off, 64);
    obj += __shfl_down(obj, off, 64);
  }
  if (tid == 0) {
    box *= (1.f / 16.f); cls *= (1.f / 16.f); obj *= (1.f / 16.f);
    out[0] = 0.05f * box + 0.5f * cls + 1.0f * obj;
    out[1] = box;
    out[2] = cls;
    out[3] = obj;
  }
}

// ---------------------------------------------------------------------------
extern "C" void kernel_launch(void* const* d_in, const int* in_sizes, int n_in,
                              void* d_out, int out_size, void* d_ws, size_t ws_size,
                              hipStream_t stream)
{
  const float* pred = (const float*)d_in[0];
  const float* tgt  = (const float*)d_in[1];
  float* out = (float*)d_out;

  char* ws = (char*)d_ws;
  float* twork        = (float*)(ws);                // 10240 B
  int*   cnt          = (int*)(ws + 10240);          // 75*16*4 = 4800 B
  int*   nnegA        = (int*)(ws + 15104);          // 4800 B (offsets 64B-padded)
  float* objP         = (float*)(ws + 19968);        // 4800 B
  float* objN         = (float*)(ws + 24832);        // 4800 B
  int*   blockOffsets = (int*)(ws + 29696);          // 4800 B
  ImgStats* stats     = (ImgStats*)(ws + 34560);     // 256 B
  unsigned long long* posBits =
      (unsigned long long*)(ws + 34816);             // 153600 B (8-aligned)
  float* p3sq         = (float*)(ws + 188416);       // 4800 B
  float* p3ce         = (float*)(ws + 193280);       // 4800 B -> ~198 KB total

  // every ws word read is written earlier this call: no memset needed.
  pass0_kernel<<<1, kB * kT, 0, stream>>>(tgt, twork);
  k1_iou_kernel<<<dim3(kNB, kB), kBlk1, 0, stream>>>(
      pred, twork, cnt, nnegA, objP, objN, posBits);
  pass2_kernel<<<dim3(kB), 512, 0, stream>>>(
      cnt, nnegA, objP, objN, blockOffsets, stats);
  k2_pos_kernel<<<dim3(kNB, kB), kBlk1, 0, stream>>>(
      pred, tgt, blockOffsets, posBits, p3sq, p3ce);
  pass4_kernel<<<1, 256, 0, stream>>>(stats, p3sq, p3ce, out);
}

// Round 8
// 115.130 us; speedup vs baseline: 1.0603x; 1.0411x over previous
//
#include <hip/hip_runtime.h>
#include <cstdint>
#include <cstddef>

// predictions: (16, 3, 160, 160, 9) fp32 -> per image N=76800 anchors x D=9
// targets:     (16, 32, 5) fp32 [cls, x, y, w, h]
// output: 4 fp32 scalars: total, box_loss, cls_loss, obj_loss
constexpr int kB     = 16;
constexpr int kN     = 76800;
constexpr int kD     = 9;
constexpr int kT     = 32;
constexpr int kBlk1  = 256;            // K1/K2 threads; 4 anchors/thread
constexpr int kApB   = 1024;           // anchors per K1/K2 block
constexpr int kNB    = kN / kApB;      // 75 blocks per image
constexpr int kWords = kN / 64;        // 1200 ballot words per image

// jax.nn.softplus(x) == max(x,0) + log1p(exp(-|x|))
__device__ __forceinline__ float softplusf(float x) {
  return fmaxf(x, 0.f) + log1pf(expf(-fabsf(x)));
}

// ---------------------------------------------------------------------------
// Pass 0: derived target boxes, SoA: twork[b][comp][j], comp={t1x,t1y,t2x,t2y,ta}
// ---------------------------------------------------------------------------
__global__ __launch_bounds__(kB * kT) void pass0_kernel(
    const float* __restrict__ tgt, float* __restrict__ twork)
{
  const int t = threadIdx.x;           // 0..511
  const int b = t >> 5, j = t & 31;
  const float* tp = tgt + ((size_t)b * kT + j) * 5;
  const float tx = tp[1], ty = tp[2], tw = tp[3], th = tp[4];
  const float t1x = tx - tw * 0.5f, t1y = ty - th * 0.5f;
  const float t2x = tx + tw * 0.5f, t2y = ty + th * 0.5f;
  float* w = twork + (size_t)b * 5 * kT;
  w[0 * kT + j] = t1x;
  w[1 * kT + j] = t1y;
  w[2 * kT + j] = t2x;
  w[3 * kT + j] = t2y;
  w[4 * kT + j] = (t2x - t1x) * (t2y - t1y);   // reference: prod(t2-t1)
}

// ---------------------------------------------------------------------------
// K1: 4 anchors/thread via 8 aligned float4 loads (fields 0-4 of each anchor;
// cls quad skipped). Division-free threshold tests. Ballot per k-slot:
// anchor = chunk*256 + 4*lane + k; word (chunk*4+k), bit = lane.
// Per-block partials to distinct slots; no atomics.  (R7 body, validated.)
// ---------------------------------------------------------------------------
__global__ __launch_bounds__(kBlk1) void k1_iou_kernel(
    const float* __restrict__ pred, const float* __restrict__ twork,
    int* __restrict__ cnt, int* __restrict__ nnegA,
    float* __restrict__ objP, float* __restrict__ objN,
    unsigned long long* __restrict__ posBits)
{
  __shared__ float s_red[4][2];
  __shared__ int   s_cnt[4][2];

  const int b    = blockIdx.y;
  const int blk  = blockIdx.x;
  const int tid  = threadIdx.x;
  const int lane = tid & 63;
  const int wv   = tid >> 6;
  const float* tw = twork + (size_t)b * 5 * kT;     // wave-uniform base

  // thread's 4 anchors: a0 = blk*1024 + wv*256 + 4*lane
  const int a0 = blk * kApB + wv * 256 + 4 * lane;
  const float4* q = reinterpret_cast<const float4*>(
      pred + ((size_t)b * kN + a0) * kD);
  const float4 q0 = q[0], q1 = q[1], q2 = q[2], q3 = q[3];
  const float4 q4 = q[4], q5 = q[5], q6 = q[6], q7 = q[7];

  // field map: anchor k flat indices 9k..9k+4
  float px[4], py[4], pw_[4], ph[4], pobj[4];
  px[0]=q0.x; py[0]=q0.y; pw_[0]=q0.z; ph[0]=q0.w; pobj[0]=q1.x;
  px[1]=q2.y; py[1]=q2.z; pw_[1]=q2.w; ph[1]=q3.x; pobj[1]=q3.y;
  px[2]=q4.z; py[2]=q4.w; pw_[2]=q5.x; ph[2]=q5.y; pobj[2]=q5.z;
  px[3]=q6.w; py[3]=q7.x; pw_[3]=q7.y; ph[3]=q7.z; pobj[3]=q7.w;

  float p1x[4], p1y[4], p2x[4], p2y[4], pa[4];
  #pragma unroll
  for (int k = 0; k < 4; ++k) {
    p1x[k] = px[k] - pw_[k] * 0.5f;  p1y[k] = py[k] - ph[k] * 0.5f;
    p2x[k] = px[k] + pw_[k] * 0.5f;  p2y[k] = py[k] + ph[k] * 0.5f;
    pa[k]  = (p2x[k] - p1x[k]) * (p2y[k] - p1y[k]);
  }

  bool posA[4] = {false,false,false,false};
  bool negA[4] = {true,true,true,true};
  #pragma unroll
  for (int j = 0; j < kT; ++j) {
    const float t1x = tw[0 * kT + j];
    const float t1y = tw[1 * kT + j];
    const float t2x = tw[2 * kT + j];
    const float t2y = tw[3 * kT + j];
    const float ta  = tw[4 * kT + j];
    #pragma unroll
    for (int k = 0; k < 4; ++k) {
      const float lox = fmaxf(p1x[k], t1x), loy = fmaxf(p1y[k], t1y);
      const float hix = fminf(p2x[k], t2x), hiy = fminf(p2y[k], t2y);
      const float inter = fmaxf(hix - lox, 0.f) * fmaxf(hiy - loy, 0.f);
      const float d = ((pa[k] + ta) - inter) + 1e-6f;   // reference eval order
      posA[k] = posA[k] || ((d >= 0.f) && (inter > 0.5f * d));
      negA[k] = negA[k] && ((d <  0.f) || (inter < 0.3f * d));
    }
  }

  float op = 0.f, on = 0.f;
  int pc = 0, nc = 0;
  const int chunk = blk * 4 + wv;                    // global 256-anchor chunk
  #pragma unroll
  for (int k = 0; k < 4; ++k) {
    op += posA[k] ? softplusf(-pobj[k]) : 0.f;
    on += negA[k] ? softplusf( pobj[k]) : 0.f;
    const unsigned long long pm = __ballot(posA[k]);
    const unsigned long long nm = __ballot(negA[k]);
    if (lane == 0)
      posBits[(size_t)b * kWords + chunk * 4 + k] = pm;
    pc += __popcll(pm);
    nc += __popcll(nm);
  }

  #pragma unroll
  for (int off = 32; off > 0; off >>= 1) {
    op += __shfl_down(op, off, 64);
    on += __shfl_down(on, off, 64);
  }
  if (lane == 0) {
    s_red[wv][0] = op;  s_red[wv][1] = on;
    s_cnt[wv][0] = pc;  s_cnt[wv][1] = nc;
  }
  __syncthreads();
  if (tid == 0) {
    float sop = 0.f, son = 0.f; int tpc = 0, tnc = 0;
    #pragma unroll
    for (int w = 0; w < 4; ++w) {
      sop += s_red[w][0]; son += s_red[w][1];
      tpc += s_cnt[w][0]; tnc += s_cnt[w][1];
    }
    const int slot = b * kNB + blk;                  // one writer, no atomics
    cnt[slot]   = tpc;
    nnegA[slot] = tnc;
    objP[slot]  = sop;
    objN[slot]  = son;
  }
}

// ---------------------------------------------------------------------------
// K2: positives only. Self-prefix: block sums cnt[b][0..blk-1] in-kernel
// (replaces the separate scan kernel). Wave wv owns chunk blk*4+wv,
// 4 anchors/thread, rank math matching K1's ballot layout (validated R7).
// ---------------------------------------------------------------------------
__global__ __launch_bounds__(kBlk1) void k2_pos_kernel(
    const float* __restrict__ pred, const float* __restrict__ tgt,
    const int* __restrict__ cnt,
    const unsigned long long* __restrict__ posBits,
    float* __restrict__ p3sq, float* __restrict__ p3ce)
{
  __shared__ float s_tx[kT], s_ty[kT];
  __shared__ int   s_tc[kT];
  __shared__ int   s_ctot[4];
  __shared__ int   s_pre[4];
  __shared__ float s_red[4][2];

  const int b = blockIdx.y, blk = blockIdx.x, tid = threadIdx.x;
  const int slot = b * kNB + blk;
  const int lane = tid & 63, wv = tid >> 6;

  // wave wv's chunk: 4 ballot words (wave-uniform address -> scalar loads)
  const unsigned long long* wp =
      posBits + (size_t)b * kWords + (blk * 4 + wv) * 4;
  const unsigned long long m0 = wp[0], m1 = wp[1], m2 = wp[2], m3 = wp[3];
  const int ctot = __popcll(m0) + __popcll(m1) + __popcll(m2) + __popcll(m3);
  if (lane == 0) s_ctot[wv] = ctot;

  // block-level exclusive prefix: sum cnt[b][t] for t < blk  (blk <= 74 < 256)
  int c = (tid < blk) ? cnt[b * kNB + tid] : 0;
  #pragma unroll
  for (int off = 32; off > 0; off >>= 1) c += __shfl_down(c, off, 64);
  if (lane == 0) s_pre[wv] = c;

  if (tid < kT) {
    const float* tp = tgt + ((size_t)b * kT + tid) * 5;
    s_tx[tid] = tp[1]; s_ty[tid] = tp[2];
    s_tc[tid] = (int)tp[0];
  }
  __syncthreads();

  int tot = 0, base = 0;
  #pragma unroll
  for (int w = 0; w < 4; ++w) { tot += s_ctot[w]; base += s_pre[w]; }
  if (tot == 0) {                                    // still define the slot
    if (tid == 0) { p3sq[slot] = 0.f; p3ce[slot] = 0.f; }
    return;
  }
  for (int w = 0; w < wv; ++w) base += s_ctot[w];

  // rank prelude for this lane within its chunk
  const unsigned long long low = ((unsigned long long)1 << lane) - 1ull;
  const int beforeLanes = __popcll(m0 & low) + __popcll(m1 & low)
                        + __popcll(m2 & low) + __popcll(m3 & low);
  const int bit0 = (int)((m0 >> lane) & 1ull);
  const int bit1 = (int)((m1 >> lane) & 1ull);
  const int bit2 = (int)((m2 >> lane) & 1ull);
  const int bit3 = (int)((m3 >> lane) & 1ull);
  const int kbit[4] = {bit0, bit1, bit2, bit3};

  const int a0 = blk * kApB + wv * 256 + 4 * lane;   // thread's first anchor
  float sqc = 0.f, cec = 0.f;
  int prior = 0;                                     // same-lane earlier-k positives
  #pragma unroll
  for (int k = 0; k < 4; ++k) {
    if (kbit[k]) {
      const int ord = base + beforeLanes + prior;
      const int tix = ord & (kT - 1);                // % 32
      const float* p = pred + ((size_t)b * kN + (a0 + k)) * kD;
      const float dx = p[0] - s_tx[tix];
      const float dy = p[1] - s_ty[tix];
      sqc += dx * dx + dy * dy;
      const float c0 = p[5], c1 = p[6], c2 = p[7], c3 = p[8];
      const float m = fmaxf(fmaxf(c0, c1), fmaxf(c2, c3));
      const float lse = m + logf(expf(c0 - m) + expf(c1 - m) + expf(c2 - m) + expf(c3 - m));
      const int tc = s_tc[tix];
      const float cv = (tc == 0) ? c0 : (tc == 1) ? c1 : (tc == 2) ? c2 : c3;
      cec += lse - cv;
    }
    prior += kbit[k];
  }

  #pragma unroll
  for (int off = 32; off > 0; off >>= 1) {
    sqc += __shfl_down(sqc, off, 64);
    cec += __shfl_down(cec, off, 64);
  }
  if (lane == 0) { s_red[wv][0] = sqc; s_red[wv][1] = cec; }
  __syncthreads();
  if (tid == 0) {
    float ss = 0.f, cs = 0.f;
    #pragma unroll
    for (int w = 0; w < 4; ++w) { ss += s_red[w][0]; cs += s_red[w][1]; }
    p3sq[slot] = ss;                                 // plain store
    p3ce[slot] = cs;
  }
}

// ---------------------------------------------------------------------------
// K3: reduce all 6 per-block partial arrays (75/image), finalize 4 scalars.
// 256 threads: image b = tid&15, stride-group g = tid>>4.
// ---------------------------------------------------------------------------
__global__ __launch_bounds__(256) void k3_final_kernel(
    const int* __restrict__ cnt, const int* __restrict__ nnegA,
    const float* __restrict__ objP, const float* __restrict__ objN,
    const float* __restrict__ p3sq, const float* __restrict__ p3ce,
    float* __restrict__ out)
{
  __shared__ float s_sq[16][17], s_ce[16][17], s_op[16][17], s_on[16][17];
  __shared__ int   s_np[16][17], s_nn[16][17];
  const int tid = threadIdx.x;
  const int b = tid & 15, g = tid >> 4;              // image, group
  int   np = 0, nn = 0;
  float op = 0.f, on = 0.f, sq = 0.f, ce = 0.f;
  for (int k = g; k < kNB; k += 16) {
    const int s = b * kNB + k;
    np += cnt[s];  nn += nnegA[s];
    op += objP[s]; on += objN[s];
    sq += p3sq[s]; ce += p3ce[s];
  }
  s_np[g][b] = np; s_nn[g][b] = nn;
  s_op[g][b] = op; s_on[g][b] = on;
  s_sq[g][b] = sq; s_ce[g][b] = ce;
  __syncthreads();

  float box = 0.f, cls = 0.f, obj = 0.f;
  if (tid < kB) {
    int tnp = 0, tnn = 0;
    float top = 0.f, ton = 0.f, tsq = 0.f, tce = 0.f;
    #pragma unroll
    for (int gg = 0; gg < 16; ++gg) {
      tnp += s_np[gg][tid]; tnn += s_nn[gg][tid];
      top += s_op[gg][tid]; ton += s_on[gg][tid];
      tsq += s_sq[gg][tid]; tce += s_ce[gg][tid];
    }
    const float np_ = (float)tnp;
    const float nn_ = (float)tnn;
    if (np_ > 0.f) {
      box = tsq / (2.0f * np_);
      cls = tce / np_;
      obj = top / np_;
    }
    if (nn_ > 0.f) obj += ton / nn_;
  }
  #pragma unroll
  for (int off = 8; off > 0; off >>= 1) {
    box += __shfl_down(box, off, 64);
    cls += __shfl_down(cls, off, 64);
    obj += __shfl_down(obj, off, 64);
  }
  if (tid == 0) {
    box *= (1.f / 16.f); cls *= (1.f / 16.f); obj *= (1.f / 16.f);
    out[0] = 0.05f * box + 0.5f * cls + 1.0f * obj;
    out[1] = box;
    out[2] = cls;
    out[3] = obj;
  }
}

// ---------------------------------------------------------------------------
extern "C" void kernel_launch(void* const* d_in, const int* in_sizes, int n_in,
                              void* d_out, int out_size, void* d_ws, size_t ws_size,
                              hipStream_t stream)
{
  const float* pred = (const float*)d_in[0];
  const float* tgt  = (const float*)d_in[1];
  float* out = (float*)d_out;

  char* ws = (char*)d_ws;
  float* twork = (float*)(ws);                       // 10240 B
  int*   cnt   = (int*)(ws + 10240);                 // 4800 B (64B-padded slots)
  int*   nnegA = (int*)(ws + 15104);                 // 4800 B
  float* objP  = (float*)(ws + 19968);               // 4800 B
  float* objN  = (float*)(ws + 24832);               // 4800 B
  unsigned long long* posBits =
      (unsigned long long*)(ws + 29696);             // 153600 B (8-aligned)
  float* p3sq  = (float*)(ws + 183296);              // 4800 B
  float* p3ce  = (float*)(ws + 188160);              // 4800 B -> ~193 KB total

  // every ws word read is written earlier this call: no memset needed.
  pass0_kernel<<<1, kB * kT, 0, stream>>>(tgt, twork);
  k1_iou_kernel<<<dim3(kNB, kB), kBlk1, 0, stream>>>(
      pred, twork, cnt, nnegA, objP, objN, posBits);
  k2_pos_kernel<<<dim3(kNB, kB), kBlk1, 0, stream>>>(
      pred, tgt, cnt, posBits, p3sq, p3ce);
  k3_final_kernel<<<1, 256, 0, stream>>>(
      cnt, nnegA, objP, objN, p3sq, p3ce, out);
}